// Round 4
// baseline (134.204 us; speedup 1.0000x reference)
//
#include <hip/hip_runtime.h>

typedef unsigned int u32;
typedef unsigned short u16;

#define B_   2
#define CIN  256
#define COUT 256
#define PD   34
#define PLANE (PD*PD)        // 1156
#define P3   (PD*PD*PD)      // 39304
#define SPAT 32768           // 32*32*32

#define XT_BYTES ((size_t)B_ * P3 * CIN * 2)
#define WB_OFF_BYTES XT_BYTES

typedef __attribute__((ext_vector_type(8)))  short bf16x8;
typedef __attribute__((ext_vector_type(8)))  u16   u16x8;
typedef __attribute__((ext_vector_type(16))) float f32x16;

__device__ __forceinline__ u16 f2bf(float f) {
  union { float f; u32 u; } v; v.f = f;
  u32 r = v.u + 0x7FFFu + ((v.u >> 16) & 1u);   // RNE
  return (u16)(r >> 16);
}

__device__ __forceinline__ void gload_lds16(const void* g, void* l) {
  __builtin_amdgcn_global_load_lds(
      (const __attribute__((address_space(1))) u32*)g,
      (__attribute__((address_space(3))) u32*)l,
      16, 0, 0);
}

__device__ __forceinline__ int tapOff(u32 d) {
  return (d == 1) ? -PLANE : (d == 2) ? PLANE
       : (d == 3) ? -PD    : (d == 4) ? PD
       : (d == 5) ? -1     : (d == 6) ? 1 : 0;
}

// ---------------- W fp32 -> bf16 --------------------------------------------
__global__ void convert_w(const float* __restrict__ W, u16* __restrict__ wb) {
  u32 idx = (blockIdx.x * 256u + threadIdx.x) * 8u;
  float4 f0 = ((const float4*)(W + idx))[0];
  float4 f1 = ((const float4*)(W + idx))[1];
  u16x8 v;
  v[0] = f2bf(f0.x); v[1] = f2bf(f0.y); v[2] = f2bf(f0.z); v[3] = f2bf(f0.w);
  v[4] = f2bf(f1.x); v[5] = f2bf(f1.y); v[6] = f2bf(f1.z); v[7] = f2bf(f1.w);
  *(u16x8*)(wb + idx) = v;
}

// ------- x (b,i,t,r,c) fp32 -> padded k-major bf16 x_t[b][p][i] -------------
__global__ void transpose_pad(const float* __restrict__ x, u16* __restrict__ xt) {
  __shared__ __align__(16) u16 tile[32][256];
  u32 wg = blockIdx.x;                       // 2048 = B*32*32
  u32 b = wg >> 10, t = (wg >> 5) & 31, r = wg & 31;
  u32 i = threadIdx.x;
  const float* src = x + ((size_t)(b * CIN + i) * SPAT + t * 1024u + r * 32u);
#pragma unroll
  for (int q = 0; q < 8; ++q) {
    float4 f = ((const float4*)src)[q];
    tile[q * 4 + 0][i] = f2bf(f.x);
    tile[q * 4 + 1][i] = f2bf(f.y);
    tile[q * 4 + 2][i] = f2bf(f.z);
    tile[q * 4 + 3][i] = f2bf(f.w);
  }
  __syncthreads();
  u32 c = threadIdx.x >> 3, chunk = threadIdx.x & 7;
  size_t p = (size_t)b * P3 + (size_t)((t + 1) * PD + (r + 1)) * PD + 1 + c;
  uint4* dst = (uint4*)(xt + p * CIN + chunk * 32u);
  const uint4* s = (const uint4*)&tile[c][chunk * 32u];
  dst[0] = s[0]; dst[1] = s[1]; dst[2] = s[2]; dst[3] = s[3];
}

// ---------------- main: 8-wave 256x256 tile, 32x32x16 MFMA, dbuf ------------
// K = 7 taps x 256 = 28 K-tiles of BK=64. Per tile per wave: 8 gload_lds
// (prefetch next tile, issued FIRST), 24 ds_read_b128, 32 MFMA(32x32x16),
// one __syncthreads (vmcnt drain is free: loads issued a full tile earlier).
__global__ __launch_bounds__(512, 2)
void conv_main(const u16* __restrict__ xt, const u16* __restrict__ wb,
               float* __restrict__ out) {
  // [buf][A=0/B=1][kb(8)][row(256)][8]  = 128 KiB
  __shared__ __align__(16) u16 lds[2][2][8][256][8];

  u32 bid = blockIdx.x;
  u32 id2 = (bid & 7) * 32u + (bid >> 3);    // XCD swizzle (256 % 8 == 0)
  u32 b  = id2 >> 7;
  u32 t  = (id2 >> 2) & 31;
  u32 r0 = (id2 & 3) * 8u;

  u32 tid = threadIdx.x;
  u32 lane = tid & 63, wave = tid >> 6;
  u32 wm = wave >> 2, wn = wave & 3;         // 2(m) x 4(n) wave grid

  const u16* xb = xt + (size_t)b * P3 * CIN;
  u32 pBase = ((t + 1) * PD + (r0 + 1)) * PD + 1;

  // staging offsets: wave w stages kb = w; chunk i covers rows/slots i*64+lane
  u32 aOff[4], bOff[4];
#pragma unroll
  for (int i = 0; i < 4; ++i) {
    u32 n = i * 64u + lane;
    aOff[i] = n * CIN + wave * 8u;
    bOff[i] = (pBase + (n >> 5) * PD + (n & 31)) * CIN + wave * 8u;
  }

#define STAGE(KT) do {                                                        \
    u32 kt_ = (u32)(KT), buf_ = kt_ & 1u;                                     \
    const u16* gA_ = wb + (size_t)(kt_ >> 2) * (COUT * CIN) + (kt_ & 3u) * 64u;\
    const u16* gB_ = xb + (ptrdiff_t)((int)((kt_ & 3u) * 64u)                 \
                                      + tapOff(kt_ >> 2) * (int)CIN);         \
    _Pragma("unroll")                                                         \
    for (int i_ = 0; i_ < 4; ++i_) {                                          \
      gload_lds16(gA_ + aOff[i_], &lds[buf_][0][wave][i_ * 64][0]);           \
      gload_lds16(gB_ + bOff[i_], &lds[buf_][1][wave][i_ * 64][0]);           \
    }                                                                         \
  } while (0)

  f32x16 acc[4][2];
#pragma unroll
  for (int i = 0; i < 4; ++i)
#pragma unroll
    for (int j = 0; j < 2; ++j) acc[i][j] = (f32x16)0.0f;

  // per-lane LDS read bases (u16 units). A frag for 32x32x16: row = lane&31,
  // kb-half = lane>>5. frag(ks,mt) at base + ks*4096 + mt*256.
  const u16* pA0 = &lds[0][0][lane >> 5][wm * 128 + (lane & 31)][0];
  const u16* pB0 = &lds[0][1][lane >> 5][wn * 64  + (lane & 31)][0];

#define COMPUTE(BUF) do {                                                     \
    const u16* pA_ = pA0 + (BUF) * 32768;                                     \
    const u16* pB_ = pB0 + (BUF) * 32768;                                     \
    _Pragma("unroll")                                                         \
    for (int ks = 0; ks < 4; ++ks) {                                          \
      bf16x8 a0 = *(const bf16x8*)(pA_ + ks * 4096);                          \
      bf16x8 a1 = *(const bf16x8*)(pA_ + ks * 4096 + 256);                    \
      bf16x8 a2 = *(const bf16x8*)(pA_ + ks * 4096 + 512);                    \
      bf16x8 a3 = *(const bf16x8*)(pA_ + ks * 4096 + 768);                    \
      bf16x8 b0 = *(const bf16x8*)(pB_ + ks * 4096);                          \
      bf16x8 b1 = *(const bf16x8*)(pB_ + ks * 4096 + 256);                    \
      __builtin_amdgcn_s_setprio(1);                                          \
      acc[0][0] = __builtin_amdgcn_mfma_f32_32x32x16_bf16(a0, b0, acc[0][0], 0, 0, 0); \
      acc[0][1] = __builtin_amdgcn_mfma_f32_32x32x16_bf16(a0, b1, acc[0][1], 0, 0, 0); \
      acc[1][0] = __builtin_amdgcn_mfma_f32_32x32x16_bf16(a1, b0, acc[1][0], 0, 0, 0); \
      acc[1][1] = __builtin_amdgcn_mfma_f32_32x32x16_bf16(a1, b1, acc[1][1], 0, 0, 0); \
      acc[2][0] = __builtin_amdgcn_mfma_f32_32x32x16_bf16(a2, b0, acc[2][0], 0, 0, 0); \
      acc[2][1] = __builtin_amdgcn_mfma_f32_32x32x16_bf16(a2, b1, acc[2][1], 0, 0, 0); \
      acc[3][0] = __builtin_amdgcn_mfma_f32_32x32x16_bf16(a3, b0, acc[3][0], 0, 0, 0); \
      acc[3][1] = __builtin_amdgcn_mfma_f32_32x32x16_bf16(a3, b1, acc[3][1], 0, 0, 0); \
      __builtin_amdgcn_s_setprio(0);                                          \
    }                                                                         \
  } while (0)

  STAGE(0);
  __syncthreads();

#pragma unroll 1
  for (int kt2 = 0; kt2 < 14; ++kt2) {
    int kt = kt2 * 2;
    STAGE(kt + 1);                  // -> buf1 (write-only this tile)
    COMPUTE(0);
    __syncthreads();
    if (kt + 2 < 28) STAGE(kt + 2); // -> buf0
    COMPUTE(1);
    __syncthreads();
  }

#undef STAGE
#undef COMPUTE

  // epilogue: 32x32 C/D: col = lane&31 (n), row = (reg&3)+8*(reg>>2)+4*(lane>>5)
  u32 colg = lane & 31u;
  u32 rbase = (lane >> 5) * 4u;
  float* ob = out + (size_t)(b * COUT + wm * 128u) * SPAT
                  + t * 1024u + r0 * 32u + wn * 64u + colg;
#pragma unroll
  for (int mt = 0; mt < 4; ++mt)
#pragma unroll
    for (int nt = 0; nt < 2; ++nt) {
      f32x16 v = acc[mt][nt];
#pragma unroll
      for (int reg = 0; reg < 16; ++reg) {
        u32 row = (u32)(reg & 3) + 8u * (u32)(reg >> 2) + rbase;
        ob[(size_t)(mt * 32u + row) * SPAT + nt * 32u] = v[reg];
      }
    }
}

extern "C" void kernel_launch(void* const* d_in, const int* in_sizes, int n_in,
                              void* d_out, int out_size, void* d_ws, size_t ws_size,
                              hipStream_t stream) {
  const float* x = (const float*)d_in[0];
  const float* W = (const float*)d_in[1];
  float* out = (float*)d_out;
  u16* xt  = (u16*)d_ws;
  u16* wbf = (u16*)((char*)d_ws + WB_OFF_BYTES);

  hipMemsetAsync(d_ws, 0, XT_BYTES, stream);
  hipLaunchKernelGGL(convert_w,     dim3(224),  dim3(256), 0, stream, W, wbf);
  hipLaunchKernelGGL(transpose_pad, dim3(2048), dim3(256), 0, stream, x, xt);
  hipLaunchKernelGGL(conv_main,     dim3(256),  dim3(512), 0, stream, xt, wbf, out);
}

// Round 5
// 110.487 us; speedup vs baseline: 1.2147x; 1.2147x over previous
//
#include <hip/hip_runtime.h>

typedef unsigned int u32;
typedef unsigned short u16;

#define B_   2
#define CIN  256
#define COUT 256
#define PD   34
#define PLANE (PD*PD)        // 1156
#define P3   (PD*PD*PD)      // 39304
#define SPAT 32768           // 32*32*32

#define XT_BYTES ((size_t)B_ * P3 * CIN * 2)
#define WB_OFF_BYTES XT_BYTES

typedef __attribute__((ext_vector_type(8)))  short bf16x8;
typedef __attribute__((ext_vector_type(8)))  u16   u16x8;
typedef __attribute__((ext_vector_type(16))) float f32x16;

__device__ __forceinline__ u16 f2bf(float f) {
  union { float f; u32 u; } v; v.f = f;
  u32 r = v.u + 0x7FFFu + ((v.u >> 16) & 1u);   // RNE
  return (u16)(r >> 16);
}

__device__ __forceinline__ void gload_lds16(const void* g, void* l) {
  __builtin_amdgcn_global_load_lds(
      (const __attribute__((address_space(1))) u32*)g,
      (__attribute__((address_space(3))) u32*)l,
      16, 0, 0);
}

__device__ __forceinline__ int tapOff(u32 d) {
  return (d == 1) ? -PLANE : (d == 2) ? PLANE
       : (d == 3) ? -PD    : (d == 4) ? PD
       : (d == 5) ? -1     : (d == 6) ? 1 : 0;
}

// ---------------- zero only the pad border of x_t ---------------------------
__global__ void zero_border(u16* __restrict__ xt) {
  u32 idx = blockIdx.x * 256u + threadIdx.x;   // covers 2*P3*32
  if (idx >= 2u * P3 * 32u) return;
  u32 oct = idx & 31u;
  u32 ps  = idx >> 5;                          // 0 .. 2*P3-1
  u32 p   = (ps >= P3) ? ps - P3 : ps;
  u32 t = p / PLANE, rem = p - t * PLANE, r = rem / PD, c = rem - r * PD;
  if (!((t == 0) | (t == 33) | (r == 0) | (r == 33) | (c == 0) | (c == 33)))
    return;
  *(u16x8*)(xt + (size_t)ps * CIN + oct * 8u) = (u16x8)0;
}

// ---------------- W fp32 -> bf16 --------------------------------------------
__global__ void convert_w(const float* __restrict__ W, u16* __restrict__ wb) {
  u32 idx = (blockIdx.x * 256u + threadIdx.x) * 8u;
  float4 f0 = ((const float4*)(W + idx))[0];
  float4 f1 = ((const float4*)(W + idx))[1];
  u16x8 v;
  v[0] = f2bf(f0.x); v[1] = f2bf(f0.y); v[2] = f2bf(f0.z); v[3] = f2bf(f0.w);
  v[4] = f2bf(f1.x); v[5] = f2bf(f1.y); v[6] = f2bf(f1.z); v[7] = f2bf(f1.w);
  *(u16x8*)(wb + idx) = v;
}

// ------- x (b,i,t,r,c) fp32 -> padded k-major bf16 x_t[b][p][i] -------------
__global__ void transpose_pad(const float* __restrict__ x, u16* __restrict__ xt) {
  __shared__ __align__(16) u16 tile[32][256];
  u32 wg = blockIdx.x;                       // 2048 = B*32*32
  u32 b = wg >> 10, t = (wg >> 5) & 31, r = wg & 31;
  u32 i = threadIdx.x;
  const float* src = x + ((size_t)(b * CIN + i) * SPAT + t * 1024u + r * 32u);
#pragma unroll
  for (int q = 0; q < 8; ++q) {
    float4 f = ((const float4*)src)[q];
    tile[q * 4 + 0][i] = f2bf(f.x);
    tile[q * 4 + 1][i] = f2bf(f.y);
    tile[q * 4 + 2][i] = f2bf(f.z);
    tile[q * 4 + 3][i] = f2bf(f.w);
  }
  __syncthreads();
  u32 c = threadIdx.x >> 3, chunk = threadIdx.x & 7;
  size_t p = (size_t)b * P3 + (size_t)((t + 1) * PD + (r + 1)) * PD + 1 + c;
  uint4* dst = (uint4*)(xt + p * CIN + chunk * 32u);
  const uint4* s = (const uint4*)&tile[c][chunk * 32u];
  dst[0] = s[0]; dst[1] = s[1]; dst[2] = s[2]; dst[3] = s[3];
}

// ---------------- main: 8-wave 256x256 tile, 32x32x16 MFMA -----------------
// 4-phase counted-vmcnt pipeline. K = 28 tiles of BK=64; phase p consumes
// kb {2p,2p+1} of buf and stages the SAME kb-pair of tile kt+1 into buf^1
// (wave w stages kb=2p+(w&1), rows (w>>1)*64+lane). vmcnt(6) + 1 barrier per
// phase: a load has ~1 full K-tile to land. Drain-0 only before tile 27.
__global__ __launch_bounds__(512, 2)
void conv_main(const u16* __restrict__ xt, const u16* __restrict__ wb,
               float* __restrict__ out) {
  // [buf][A=0/B=1][kb(8)][row(256)][8]  = 128 KiB
  __shared__ __align__(16) u16 lds[2][2][8][256][8];

  u32 bid = blockIdx.x;
  u32 id2 = (bid & 7) * 32u + (bid >> 3);    // XCD swizzle (256 % 8 == 0)
  u32 b  = id2 >> 7;
  u32 t  = (id2 >> 2) & 31;
  u32 r0 = (id2 & 3) * 8u;

  u32 tid = threadIdx.x;
  u32 lane = tid & 63, wave = tid >> 6;
  u32 wm = wave >> 2, wn = wave & 3;         // 2(m) x 4(n) wave grid
  u32 chunk = wave >> 1, kpar = wave & 1;    // staging role

  const u16* xb = xt + (size_t)b * P3 * CIN;
  u32 pBase = ((t + 1) * PD + (r0 + 1)) * PD + 1;

  u32 n = chunk * 64u + lane;
  u32 aOffBase = n * CIN + kpar * 8u;
  u32 bOffBase = (pBase + (n >> 5) * PD + (n & 31)) * CIN + kpar * 8u;

  f32x16 acc[4][2];
#pragma unroll
  for (int i = 0; i < 4; ++i)
#pragma unroll
    for (int j = 0; j < 2; ++j) acc[i][j] = (f32x16)0.0f;

  // per-lane LDS read bases (u16 units). strides: buf 32768, A/B 16384,
  // kb 2048, row 8. frag(ks=p, mt): + buf*32768 + p*4096 + mt*256.
  const u16* pA = &lds[0][0][lane >> 5][wm * 128 + (lane & 31)][0];
  const u16* pB = &lds[0][1][lane >> 5][wn * 64 + (lane & 31)][0];

#define MF(A, Bv, C) __builtin_amdgcn_mfma_f32_32x32x16_bf16(A, Bv, C, 0, 0, 0)

#define PHASE_BODY(BUF, P) {                                                  \
    bf16x8 a0 = *(const bf16x8*)(pA + (BUF) * 32768 + (P) * 4096);            \
    bf16x8 a1 = *(const bf16x8*)(pA + (BUF) * 32768 + (P) * 4096 + 256);      \
    bf16x8 a2 = *(const bf16x8*)(pA + (BUF) * 32768 + (P) * 4096 + 512);      \
    bf16x8 a3 = *(const bf16x8*)(pA + (BUF) * 32768 + (P) * 4096 + 768);      \
    bf16x8 b0 = *(const bf16x8*)(pB + (BUF) * 32768 + (P) * 4096);            \
    bf16x8 b1 = *(const bf16x8*)(pB + (BUF) * 32768 + (P) * 4096 + 256);      \
    __builtin_amdgcn_s_setprio(1);                                            \
    acc[0][0] = MF(a0, b0, acc[0][0]);                                        \
    acc[0][1] = MF(a0, b1, acc[0][1]);                                        \
    acc[1][0] = MF(a1, b0, acc[1][0]);                                        \
    acc[1][1] = MF(a1, b1, acc[1][1]);                                        \
    acc[2][0] = MF(a2, b0, acc[2][0]);                                        \
    acc[2][1] = MF(a2, b1, acc[2][1]);                                        \
    acc[3][0] = MF(a3, b0, acc[3][0]);                                        \
    acc[3][1] = MF(a3, b1, acc[3][1]);                                        \
    __builtin_amdgcn_s_setprio(0);                                            \
  }

#define PHASE(P) do {                                                         \
    asm volatile("s_waitcnt vmcnt(6)" ::: "memory");                          \
    __builtin_amdgcn_s_barrier();                                             \
    __builtin_amdgcn_sched_barrier(0);                                        \
    gload_lds16(gA + (P) * 16, dA + (P) * 4096);                              \
    gload_lds16(gB + (P) * 16, dB + (P) * 4096);                              \
    PHASE_BODY(buf, P)                                                        \
  } while (0)

  // prologue: stage tile 0 in phase order (A,B per phase slot) -> 8 in flight
  {
    const u16* gA = wb + aOffBase;           // kt=0: d=0, kc=0, tapOff=0
    const u16* gB = xb + bOffBase;
    u16* dA = &lds[0][0][kpar][chunk * 64][0];
    u16* dB = &lds[0][1][kpar][chunk * 64][0];
#pragma unroll
    for (int p = 0; p < 4; ++p) {
      gload_lds16(gA + p * 16, dA + p * 4096);
      gload_lds16(gB + p * 16, dB + p * 4096);
    }
  }

#pragma unroll 1
  for (int kt = 0; kt < 27; ++kt) {
    u32 buf = (u32)kt & 1u;
    u32 kn  = (u32)kt + 1u;
    u32 nb  = kn & 1u;
    const u16* gA = wb + (size_t)(kn >> 2) * (COUT * CIN) + (kn & 3u) * 64u + aOffBase;
    const u16* gB = xb + (ptrdiff_t)((int)((kn & 3u) * 64u)
                                     + tapOff(kn >> 2) * (int)CIN) + bOffBase;
    u16* dA = &lds[nb][0][kpar][chunk * 64][0];
    u16* dB = &lds[nb][1][kpar][chunk * 64][0];
    PHASE(0);
    PHASE(1);
    PHASE(2);
    PHASE(3);
  }

  // tail: tile 27 (buf = 1), everything already issued -> drain once
  asm volatile("s_waitcnt vmcnt(0)" ::: "memory");
  __builtin_amdgcn_s_barrier();
  __builtin_amdgcn_sched_barrier(0);
  PHASE_BODY(1, 0)
  PHASE_BODY(1, 1)
  PHASE_BODY(1, 2)
  PHASE_BODY(1, 3)

#undef PHASE
#undef PHASE_BODY
#undef MF

  // epilogue: 32x32 C/D: col = lane&31 (n), row = (reg&3)+8*(reg>>2)+4*(lane>>5)
  u32 colg = lane & 31u;
  u32 rbase = (lane >> 5) * 4u;
  float* ob = out + (size_t)(b * COUT + wm * 128u) * SPAT
                  + t * 1024u + r0 * 32u + wn * 64u + colg;
#pragma unroll
  for (int mt = 0; mt < 4; ++mt)
#pragma unroll
    for (int nt = 0; nt < 2; ++nt) {
      f32x16 v = acc[mt][nt];
#pragma unroll
      for (int reg = 0; reg < 16; ++reg) {
        u32 row = (u32)(reg & 3) + 8u * (u32)(reg >> 2) + rbase;
        ob[(size_t)(mt * 32u + row) * SPAT + nt * 32u] = v[reg];
      }
    }
}

extern "C" void kernel_launch(void* const* d_in, const int* in_sizes, int n_in,
                              void* d_out, int out_size, void* d_ws, size_t ws_size,
                              hipStream_t stream) {
  const float* x = (const float*)d_in[0];
  const float* W = (const float*)d_in[1];
  float* out = (float*)d_out;
  u16* xt  = (u16*)d_ws;
  u16* wbf = (u16*)((char*)d_ws + WB_OFF_BYTES);

  u32 zThreads = 2u * P3 * 32u;
  hipLaunchKernelGGL(zero_border,   dim3((zThreads + 255) / 256), dim3(256), 0, stream, xt);
  hipLaunchKernelGGL(convert_w,     dim3(224),  dim3(256), 0, stream, W, wbf);
  hipLaunchKernelGGL(transpose_pad, dim3(2048), dim3(256), 0, stream, x, xt);
  hipLaunchKernelGGL(conv_main,     dim3(256),  dim3(512), 0, stream, xt, wbf, out);
}

// Round 6
// 104.748 us; speedup vs baseline: 1.2812x; 1.0548x over previous
//
#include <hip/hip_runtime.h>

typedef unsigned int u32;
typedef unsigned short u16;

#define B_   2
#define CIN  256
#define COUT 256
#define PD   34
#define PLANE (PD*PD)        // 1156
#define P3   (PD*PD*PD)      // 39304
#define SPAT 32768           // 32*32*32

#define XT_BYTES ((size_t)B_ * P3 * CIN * 2)
#define WB_OFF_BYTES XT_BYTES

typedef __attribute__((ext_vector_type(8)))  short bf16x8;
typedef __attribute__((ext_vector_type(8)))  u16   u16x8;
typedef __attribute__((ext_vector_type(4)))  float f32x4;

__device__ __forceinline__ u16 f2bf(float f) {
  union { float f; u32 u; } v; v.f = f;
  u32 r = v.u + 0x7FFFu + ((v.u >> 16) & 1u);   // RNE
  return (u16)(r >> 16);
}

__device__ __forceinline__ void gload_lds16(const void* g, void* l) {
  __builtin_amdgcn_global_load_lds(
      (const __attribute__((address_space(1))) u32*)g,
      (__attribute__((address_space(3))) u32*)l,
      16, 0, 0);
}

__device__ __forceinline__ int tapOff(u32 d) {
  return (d == 1) ? -PLANE : (d == 2) ? PLANE
       : (d == 3) ? -PD    : (d == 4) ? PD
       : (d == 5) ? -1     : (d == 6) ? 1 : 0;
}

// ---------------- zero only the pad border of x_t ---------------------------
__global__ void zero_border(u16* __restrict__ xt) {
  u32 idx = blockIdx.x * 256u + threadIdx.x;   // covers 2*P3*32
  if (idx >= 2u * P3 * 32u) return;
  u32 oct = idx & 31u;
  u32 ps  = idx >> 5;                          // 0 .. 2*P3-1
  u32 p   = (ps >= P3) ? ps - P3 : ps;
  u32 t = p / PLANE, rem = p - t * PLANE, r = rem / PD, c = rem - r * PD;
  if (!((t == 0) | (t == 33) | (r == 0) | (r == 33) | (c == 0) | (c == 33)))
    return;
  *(u16x8*)(xt + (size_t)ps * CIN + oct * 8u) = (u16x8)0;
}

// ---------------- W fp32 -> bf16 --------------------------------------------
__global__ void convert_w(const float* __restrict__ W, u16* __restrict__ wb) {
  u32 idx = (blockIdx.x * 256u + threadIdx.x) * 8u;
  float4 f0 = ((const float4*)(W + idx))[0];
  float4 f1 = ((const float4*)(W + idx))[1];
  u16x8 v;
  v[0] = f2bf(f0.x); v[1] = f2bf(f0.y); v[2] = f2bf(f0.z); v[3] = f2bf(f0.w);
  v[4] = f2bf(f1.x); v[5] = f2bf(f1.y); v[6] = f2bf(f1.z); v[7] = f2bf(f1.w);
  *(u16x8*)(wb + idx) = v;
}

// ------- x (b,i,t,r,c) fp32 -> padded k-major bf16 x_t[b][p][i] -------------
__global__ void transpose_pad(const float* __restrict__ x, u16* __restrict__ xt) {
  __shared__ __align__(16) u16 tile[32][256];
  u32 wg = blockIdx.x;                       // 2048 = B*32*32
  u32 b = wg >> 10, t = (wg >> 5) & 31, r = wg & 31;
  u32 i = threadIdx.x;
  const float* src = x + ((size_t)(b * CIN + i) * SPAT + t * 1024u + r * 32u);
#pragma unroll
  for (int q = 0; q < 8; ++q) {
    float4 f = ((const float4*)src)[q];
    tile[q * 4 + 0][i] = f2bf(f.x);
    tile[q * 4 + 1][i] = f2bf(f.y);
    tile[q * 4 + 2][i] = f2bf(f.z);
    tile[q * 4 + 3][i] = f2bf(f.w);
  }
  __syncthreads();
  u32 c = threadIdx.x >> 3, chunk = threadIdx.x & 7;
  size_t p = (size_t)b * P3 + (size_t)((t + 1) * PD + (r + 1)) * PD + 1 + c;
  uint4* dst = (uint4*)(xt + p * CIN + chunk * 32u);
  const uint4* s = (const uint4*)&tile[c][chunk * 32u];
  dst[0] = s[0]; dst[1] = s[1]; dst[2] = s[2]; dst[3] = s[3];
}

// ---------------- main: 8-wave 256x256 tile, m201-style 4-quadrant phases ---
// Per K-tile (BK=64): 4 phases; each = {12 ds_read_b128 + 1 half-tile stage
// (2 gload_lds) -> barrier -> 16 MFMA 16x16x32 -> barrier}. ONE vmcnt(4) per
// tile (before last barrier); drain-0 only at T=26. LDS rows permuted so each
// quadrant's read region is contiguous:
//   A row' = mh*128 + wm*64 + s   <-> W row (2*wm+mh)*64 + s
//   B row' = nh*128 + wn*32 + j'  <-> spatial n = wn*64 + nh*32 + j'
// Stage schedule (block of tile T): p0 -> (T+1).A1', p1 -> (T+1).B0',
// p2 -> (T+2).A0', p3 -> (T+2).B1'  (each region restaged exactly one phase
// after its last read; stage->consume gap >= 4 phases, covered by vmcnt(4)).
__global__ __launch_bounds__(512, 2)
void conv_main(const u16* __restrict__ xt, const u16* __restrict__ wb,
               float* __restrict__ out) {
  // [buf][A=0/B=1][kb(8)][row'(256)][8]  = 128 KiB
  __shared__ __align__(16) u16 lds[2][2][8][256][8];

  u32 bid = blockIdx.x;
  u32 id2 = (bid & 7) * 32u + (bid >> 3);    // XCD swizzle (256 % 8 == 0)
  u32 b  = id2 >> 7;
  u32 t  = (id2 >> 2) & 31;
  u32 r0 = (id2 & 3) * 8u;

  u32 tid = threadIdx.x;
  u32 lane = tid & 63, wave = tid >> 6;
  u32 wm = wave >> 2, wn = wave & 3;         // 2(m) x 4(n) wave grid
  u32 l15 = lane & 15u, lq = lane >> 4;

  const u16* xb = xt + (size_t)b * P3 * CIN;
  u32 pBase = ((t + 1) * PD + (r0 + 1)) * PD + 1;

  // staging source bases (element units); wave w stages kb=w (k-offset w*8)
  u32 aBase = lane * CIN + wave * 8u;
  u32 bBase = (pBase + 2u * (lane >> 5) * PD + (lane & 31u)) * CIN + wave * 8u;

  // A-half H: call c covers W rows (2c+H)*64+lane -> LDS rows' H*128+c*64+lane
#define STAGE_A(KN, H) do {                                                   \
    u32 kn_ = (u32)(KN);                                                      \
    const u16* g_ = wb + (size_t)(kn_ >> 2) * (COUT * CIN)                    \
                       + (kn_ & 3u) * 64u + aBase + (H) * 16384u;             \
    u16* d_ = &lds[kn_ & 1u][0][wave][(H) * 128][0];                          \
    gload_lds16(g_, d_);                                                      \
    gload_lds16(g_ + 32768u, d_ + 512);                                       \
  } while (0)

  // B-half H: call c covers n = H*32 + (2c+(l>>5))*64 + (l&31)
#define STAGE_B(KN, H) do {                                                   \
    u32 kn_ = (u32)(KN);                                                      \
    const u16* g_ = xb + (ptrdiff_t)((int)((kn_ & 3u) * 64u)                  \
                       + tapOff(kn_ >> 2) * (int)CIN) + bBase                 \
                       + (H) * (u32)(PD * CIN);                               \
    u16* d_ = &lds[kn_ & 1u][1][wave][(H) * 128][0];                          \
    gload_lds16(g_, d_);                                                      \
    gload_lds16(g_ + 4u * (u32)(PD * CIN), d_ + 512);                         \
  } while (0)

  f32x4 acc[8][4];
#pragma unroll
  for (int i = 0; i < 8; ++i)
#pragma unroll
    for (int j = 0; j < 4; ++j) acc[i][j] = (f32x4)0.0f;

#define PH(MH, NH, STG, VM) do {                                              \
    bf16x8 af[2][4], bv[2][2];                                                \
    _Pragma("unroll")                                                         \
    for (int ks = 0; ks < 2; ++ks) {                                          \
      _Pragma("unroll")                                                       \
      for (int mi = 0; mi < 4; ++mi)                                          \
        af[ks][mi] = *(const bf16x8*)&lds[buf][0][ks * 4 + lq]                \
            [(MH) * 128 + wm * 64 + mi * 16 + l15][0];                        \
      _Pragma("unroll")                                                       \
      for (int ni = 0; ni < 2; ++ni)                                          \
        bv[ks][ni] = *(const bf16x8*)&lds[buf][1][ks * 4 + lq]                \
            [(NH) * 128 + wn * 32 + ni * 16 + l15][0];                        \
    }                                                                         \
    STG;                                                                      \
    __builtin_amdgcn_sched_barrier(0);                                        \
    __builtin_amdgcn_s_barrier();                                             \
    __builtin_amdgcn_sched_barrier(0);                                        \
    __builtin_amdgcn_s_setprio(1);                                            \
    _Pragma("unroll")                                                         \
    for (int ks = 0; ks < 2; ++ks)                                            \
      _Pragma("unroll")                                                       \
      for (int mi = 0; mi < 4; ++mi)                                          \
        _Pragma("unroll")                                                     \
        for (int ni = 0; ni < 2; ++ni)                                        \
          acc[(MH) * 4 + mi][(NH) * 2 + ni] =                                 \
              __builtin_amdgcn_mfma_f32_16x16x32_bf16(af[ks][mi], bv[ks][ni], \
                  acc[(MH) * 4 + mi][(NH) * 2 + ni], 0, 0, 0);                \
    __builtin_amdgcn_s_setprio(0);                                            \
    VM;                                                                       \
    __builtin_amdgcn_sched_barrier(0);                                        \
    __builtin_amdgcn_s_barrier();                                             \
    __builtin_amdgcn_sched_barrier(0);                                        \
  } while (0)

  // prologue: T0 fully + T1.{A0',B1'}; vmcnt(4) leaves only T1's 4 loads open
  STAGE_A(0, 0); STAGE_B(0, 1); STAGE_A(0, 1); STAGE_B(0, 0);
  STAGE_A(1, 0); STAGE_B(1, 1);
  asm volatile("s_waitcnt vmcnt(4)" ::: "memory");
  __builtin_amdgcn_s_barrier();
  __builtin_amdgcn_sched_barrier(0);

#pragma unroll 1
  for (int T = 0; T < 28; ++T) {
    const u32 buf = (u32)T & 1u;
    PH(0, 0, { if (T + 1 < 28) STAGE_A(T + 1, 1); }, {});
    PH(0, 1, { if (T + 1 < 28) STAGE_B(T + 1, 0); }, {});
    PH(1, 1, { if (T + 2 < 28) STAGE_A(T + 2, 0); }, {});
    PH(1, 0, { if (T + 2 < 28) STAGE_B(T + 2, 1); },
       { if (T < 26) asm volatile("s_waitcnt vmcnt(4)" ::: "memory");
         else        asm volatile("s_waitcnt vmcnt(0)" ::: "memory"); });
  }

#undef PH
#undef STAGE_A
#undef STAGE_B

  // epilogue: C/D of 16x16: row = lq*4 + reg (cout), col = l15 (spatial)
  // cout = (2*wm+mh)*64 + mi*16 + lq*4 + reg ; n = wn*64 + nh*32 + ni*16 + l15
#pragma unroll
  for (int mh = 0; mh < 2; ++mh)
#pragma unroll
    for (int mi = 0; mi < 4; ++mi) {
      u32 cout = (2u * wm + (u32)mh) * 64u + (u32)mi * 16u + lq * 4u;
      float* orow = out + (size_t)(b * COUT + cout) * SPAT
                        + t * 1024u + r0 * 32u;
#pragma unroll
      for (int nh = 0; nh < 2; ++nh)
#pragma unroll
        for (int ni = 0; ni < 2; ++ni) {
          f32x4 v = acc[mh * 4 + mi][nh * 2 + ni];
          u32 n = wn * 64u + (u32)nh * 32u + (u32)ni * 16u + l15;
#pragma unroll
          for (int rg = 0; rg < 4; ++rg)
            orow[(size_t)rg * SPAT + n] = v[rg];
        }
    }
}

extern "C" void kernel_launch(void* const* d_in, const int* in_sizes, int n_in,
                              void* d_out, int out_size, void* d_ws, size_t ws_size,
                              hipStream_t stream) {
  const float* x = (const float*)d_in[0];
  const float* W = (const float*)d_in[1];
  float* out = (float*)d_out;
  u16* xt  = (u16*)d_ws;
  u16* wbf = (u16*)((char*)d_ws + WB_OFF_BYTES);

  u32 zThreads = 2u * P3 * 32u;
  hipLaunchKernelGGL(zero_border,   dim3((zThreads + 255) / 256), dim3(256), 0, stream, xt);
  hipLaunchKernelGGL(convert_w,     dim3(224),  dim3(256), 0, stream, W, wbf);
  hipLaunchKernelGGL(transpose_pad, dim3(2048), dim3(256), 0, stream, x, xt);
  hipLaunchKernelGGL(conv_main,     dim3(256),  dim3(512), 0, stream, xt, wbf, out);
}

// Round 7
// 95.805 us; speedup vs baseline: 1.4008x; 1.0933x over previous
//
#include <hip/hip_runtime.h>

typedef unsigned int u32;
typedef unsigned short u16;

#define B_   2
#define CIN  256
#define COUT 256
#define PD   34
#define PLANE (PD*PD)        // 1156
#define P3   (PD*PD*PD)      // 39304
#define SPAT 32768           // 32*32*32

// xt2: [b][kg(32)][p(P3)][8]  (granule = 8 cin = 16B)
#define XT_BYTES ((size_t)B_ * 32 * P3 * 8 * 2)
#define WB_OFF_BYTES XT_BYTES

typedef __attribute__((ext_vector_type(8)))  short bf16x8;
typedef __attribute__((ext_vector_type(8)))  u16   u16x8;
typedef __attribute__((ext_vector_type(4)))  float f32x4;

__device__ __forceinline__ u16 f2bf(float f) {
  union { float f; u32 u; } v; v.f = f;
  u32 r = v.u + 0x7FFFu + ((v.u >> 16) & 1u);   // RNE
  return (u16)(r >> 16);
}

__device__ __forceinline__ void gload_lds16(const void* g, void* l) {
  __builtin_amdgcn_global_load_lds(
      (const __attribute__((address_space(1))) u32*)g,
      (__attribute__((address_space(3))) u32*)l,
      16, 0, 0);
}

__device__ __forceinline__ int tapOff(u32 d) {
  return (d == 1) ? -PLANE : (d == 2) ? PLANE
       : (d == 3) ? -PD    : (d == 4) ? PD
       : (d == 5) ? -1     : (d == 6) ? 1 : 0;
}

// ---------------- zero only the pad border of xt2 ---------------------------
__global__ void zero_border(u16* __restrict__ xt) {
  u32 idx = blockIdx.x * 256u + threadIdx.x;   // 64 * P3 granules
  if (idx >= 64u * (u32)P3) return;
  u32 bk = idx & 63u;                          // b*32 + kg
  u32 p  = idx >> 6;
  u32 t = p / PLANE, rem = p - t * PLANE, r = rem / PD, c = rem - r * PD;
  if (!((t == 0) | (t == 33) | (r == 0) | (r == 33) | (c == 0) | (c == 33)))
    return;
  *(u16x8*)(xt + ((size_t)bk * P3 + p) * 8) = (u16x8)0;
}

// ---------------- W fp32 -> bf16, wb2[d][kg][o][8] ---------------------------
__global__ void convert_w(const float* __restrict__ W, u16* __restrict__ wb) {
  u32 idx = blockIdx.x * 256u + threadIdx.x;   // 7*32*256 = 57344
  u32 o = idx & 255u, kgd = idx >> 8;          // kgd = d*32 + kg
  u32 kg = kgd & 31u, d = kgd >> 5;
  const float* src = W + (size_t)(d * 256u + o) * CIN + kg * 8u;
  float4 f0 = ((const float4*)src)[0];
  float4 f1 = ((const float4*)src)[1];
  u16x8 v;
  v[0] = f2bf(f0.x); v[1] = f2bf(f0.y); v[2] = f2bf(f0.z); v[3] = f2bf(f0.w);
  v[4] = f2bf(f1.x); v[5] = f2bf(f1.y); v[6] = f2bf(f1.z); v[7] = f2bf(f1.w);
  *(u16x8*)(wb + (size_t)idx * 8) = v;
}

// ------- x (b,i,t,r,c) fp32 -> xt2[b][kg][p][8] bf16 ------------------------
__global__ void transpose_pad(const float* __restrict__ x, u16* __restrict__ xt) {
  __shared__ __align__(16) u16 tile[32][256];
  u32 wg = blockIdx.x;                       // 2048 = B*32*32
  u32 b = wg >> 10, t = (wg >> 5) & 31, r = wg & 31;
  u32 i = threadIdx.x;
  const float* src = x + ((size_t)(b * CIN + i) * SPAT + t * 1024u + r * 32u);
#pragma unroll
  for (int q = 0; q < 8; ++q) {
    float4 f = ((const float4*)src)[q];
    tile[q * 4 + 0][i] = f2bf(f.x);
    tile[q * 4 + 1][i] = f2bf(f.y);
    tile[q * 4 + 2][i] = f2bf(f.z);
    tile[q * 4 + 3][i] = f2bf(f.w);
  }
  __syncthreads();
  u32 c = threadIdx.x >> 3, chunk = threadIdx.x & 7;   // chunk -> kg 4*chunk..+3
  u32 p = ((t + 1) * PD + (r + 1)) * PD + 1 + c;
  const uint4* s = (const uint4*)&tile[c][chunk * 32u];
#pragma unroll
  for (int j = 0; j < 4; ++j) {
    u32 kg = chunk * 4u + (u32)j;
    *(uint4*)(xt + ((size_t)(b * 32u + kg) * P3 + p) * 8) = s[j];
  }
}

// ---------------- main: 8-wave 256x256 tile, 4-quadrant phases --------------
// Dense staging: wave w stages kb=w; A-gload = 1024B contiguous, B-gload =
// 2x512B. Register-cached fragments: p0 reads af0+bv0, p1 bv1, p2 af1, p3 none.
// Stage schedule (of tile T): p0->(T+1).A-h1 [buf^1], p1->(T+1).B-h0 [buf^1],
// p2->(T+2).A-h0 [buf, read done p1], p3->(T+2).B-h1 [buf, read done p2].
// ONE vmcnt(4) per tile; drain-0 at T>=26.
__global__ __launch_bounds__(512, 2)
void conv_main(const u16* __restrict__ xt, const u16* __restrict__ wb,
               float* __restrict__ out) {
  // [buf][A=0/B=1][kb(8)][row'(256)][8]  = 128 KiB
  __shared__ __align__(16) u16 lds[2][2][8][256][8];

  u32 bid = blockIdx.x;
  u32 id2 = (bid & 7) * 32u + (bid >> 3);    // XCD swizzle (256 % 8 == 0)
  u32 b  = id2 >> 7;
  u32 t  = (id2 >> 2) & 31;
  u32 r0 = (id2 & 3) * 8u;

  u32 tid = threadIdx.x;
  u32 lane = tid & 63, wave = tid >> 6;
  u32 wm = wave >> 2, wn = wave & 3;         // 2(m) x 4(n) wave grid
  u32 l15 = lane & 15u, lq = lane >> 4;

  const u16* xb = xt + (size_t)b * 32u * P3 * 8u;
  u32 pBase = ((t + 1) * PD + (r0 + 1)) * PD + 1;

  u32 aLane = lane * 8u;                                   // u16 units
  u32 bLane = (2u * (lane >> 5) * (u32)PD + (lane & 31u)) * 8u;

  // A rows' H*128 + c*64 + l  <->  W cout (2c+H)*64 + l
#define STAGE_A(KN, H) do {                                                   \
    u32 kn_ = (u32)(KN);                                                      \
    const u16* g_ = wb + ((size_t)((kn_ >> 2) * 32u + (kn_ & 3u) * 8u + wave) \
                          * 256u + (H) * 64u) * 8u + aLane;                   \
    u16* d_ = &lds[kn_ & 1u][0][wave][(H) * 128][0];                          \
    gload_lds16(g_, d_);                                                      \
    gload_lds16(g_ + 1024u, d_ + 512u);                                       \
  } while (0)

  // B rows' H*128 + c*64 + l <-> n = (2c+(l>>5))*64 + H*32 + (l&31)
  //   -> rrow = 4c + 2*(l>>5) + H, col = l&31
#define STAGE_B(KN, H) do {                                                   \
    u32 kn_ = (u32)(KN);                                                      \
    u32 kg_ = (kn_ & 3u) * 8u + wave;                                         \
    const u16* g_ = xb + ((size_t)kg_ * P3                                    \
                          + (u32)((int)pBase + tapOff(kn_ >> 2))              \
                          + (H) * (u32)PD) * 8u + bLane;                      \
    u16* d_ = &lds[kn_ & 1u][1][wave][(H) * 128][0];                          \
    gload_lds16(g_, d_);                                                      \
    gload_lds16(g_ + (u32)(4 * PD * 8), d_ + 512u);                           \
  } while (0)

#define LDA(DST, MH)                                                          \
    _Pragma("unroll")                                                         \
    for (int ks = 0; ks < 2; ++ks)                                            \
      _Pragma("unroll")                                                       \
      for (int mi = 0; mi < 4; ++mi)                                          \
        DST[ks][mi] = *(const bf16x8*)&lds[buf][0][ks * 4 + lq]               \
            [(MH) * 128 + wm * 64 + mi * 16 + l15][0];

#define LDB(DST, NH)                                                          \
    _Pragma("unroll")                                                         \
    for (int ks = 0; ks < 2; ++ks)                                            \
      _Pragma("unroll")                                                       \
      for (int ni = 0; ni < 2; ++ni)                                          \
        DST[ks][ni] = *(const bf16x8*)&lds[buf][1][ks * 4 + lq]               \
            [(NH) * 128 + wn * 32 + ni * 16 + l15][0];

#define MMA(AF, BV, MH, NH) do {                                              \
    __builtin_amdgcn_s_setprio(1);                                            \
    _Pragma("unroll")                                                         \
    for (int ks = 0; ks < 2; ++ks)                                            \
      _Pragma("unroll")                                                       \
      for (int mi = 0; mi < 4; ++mi)                                          \
        _Pragma("unroll")                                                     \
        for (int ni = 0; ni < 2; ++ni)                                        \
          acc[(MH) * 4 + mi][(NH) * 2 + ni] =                                 \
              __builtin_amdgcn_mfma_f32_16x16x32_bf16(AF[ks][mi], BV[ks][ni], \
                  acc[(MH) * 4 + mi][(NH) * 2 + ni], 0, 0, 0);                \
    __builtin_amdgcn_s_setprio(0);                                            \
  } while (0)

#define BAR() do { __builtin_amdgcn_sched_barrier(0);                         \
                   __builtin_amdgcn_s_barrier();                              \
                   __builtin_amdgcn_sched_barrier(0); } while (0)

  f32x4 acc[8][4];
#pragma unroll
  for (int i = 0; i < 8; ++i)
#pragma unroll
    for (int j = 0; j < 4; ++j) acc[i][j] = (f32x4)0.0f;

  bf16x8 af0[2][4], af1[2][4], bv0[2][2], bv1[2][2];

  // prologue: T0 fully; then T1.A-h0, T1.B-h1 (steady-state leftovers)
  STAGE_A(0, 0); STAGE_A(0, 1); STAGE_B(0, 0); STAGE_B(0, 1);
  STAGE_A(1, 0); STAGE_B(1, 1);
  asm volatile("s_waitcnt vmcnt(4)" ::: "memory");
  __builtin_amdgcn_s_barrier();
  __builtin_amdgcn_sched_barrier(0);

#pragma unroll 1
  for (int T = 0; T < 28; ++T) {
    const u32 buf = (u32)T & 1u;
    // p0: read af0, bv0; stage (T+1).A-h1 -> buf^1
    LDA(af0, 0); LDB(bv0, 0);
    if (T + 1 < 28) STAGE_A(T + 1, 1);
    BAR();
    MMA(af0, bv0, 0, 0);
    BAR();
    // p1: read bv1; stage (T+1).B-h0 -> buf^1
    LDB(bv1, 1);
    if (T + 1 < 28) STAGE_B(T + 1, 0);
    BAR();
    MMA(af0, bv1, 0, 1);
    BAR();
    // p2: read af1; stage (T+2).A-h0 -> buf (A-h0 reads finished at p0)
    LDA(af1, 1);
    if (T + 2 < 28) STAGE_A(T + 2, 0);
    BAR();
    MMA(af1, bv1, 1, 1);
    BAR();
    // p3: no reads; stage (T+2).B-h1 -> buf (B-h1 reads finished at p1)
    if (T + 2 < 28) STAGE_B(T + 2, 1);
    BAR();
    MMA(af1, bv0, 1, 0);
    if (T < 26) asm volatile("s_waitcnt vmcnt(4)" ::: "memory");
    else        asm volatile("s_waitcnt vmcnt(0)" ::: "memory");
    BAR();
  }

#undef BAR
#undef MMA
#undef LDB
#undef LDA
#undef STAGE_B
#undef STAGE_A

  // epilogue: C/D of 16x16: row = lq*4 + reg (cout), col = l15 (spatial)
  // cout = (2*wm+mh)*64 + mi*16 + lq*4 + reg ; n = wn*64 + nh*32 + ni*16 + l15
#pragma unroll
  for (int mh = 0; mh < 2; ++mh)
#pragma unroll
    for (int mi = 0; mi < 4; ++mi) {
      u32 cout = (2u * wm + (u32)mh) * 64u + (u32)mi * 16u + lq * 4u;
      float* orow = out + (size_t)(b * COUT + cout) * SPAT
                        + t * 1024u + r0 * 32u;
#pragma unroll
      for (int nh = 0; nh < 2; ++nh)
#pragma unroll
        for (int ni = 0; ni < 2; ++ni) {
          f32x4 v = acc[mh * 4 + mi][nh * 2 + ni];
          u32 n = wn * 64u + (u32)nh * 32u + (u32)ni * 16u + l15;
#pragma unroll
          for (int rg = 0; rg < 4; ++rg)
            orow[(size_t)rg * SPAT + n] = v[rg];
        }
    }
}

extern "C" void kernel_launch(void* const* d_in, const int* in_sizes, int n_in,
                              void* d_out, int out_size, void* d_ws, size_t ws_size,
                              hipStream_t stream) {
  const float* x = (const float*)d_in[0];
  const float* W = (const float*)d_in[1];
  float* out = (float*)d_out;
  u16* xt  = (u16*)d_ws;
  u16* wbf = (u16*)((char*)d_ws + WB_OFF_BYTES);

  u32 zThreads = 64u * (u32)P3;
  hipLaunchKernelGGL(zero_border,   dim3((zThreads + 255) / 256), dim3(256), 0, stream, xt);
  hipLaunchKernelGGL(convert_w,     dim3(224),  dim3(256), 0, stream, W, wbf);
  hipLaunchKernelGGL(transpose_pad, dim3(2048), dim3(256), 0, stream, x, xt);
  hipLaunchKernelGGL(conv_main,     dim3(256),  dim3(512), 0, stream, xt, wbf, out);
}